// Round 3
// baseline (225.750 us; speedup 1.0000x reference)
//
#include <hip/hip_runtime.h>

// Quantized SiLU, S=8192 x H=4096, per-row scales.
//   x_f = x*sx[r]; y_q = clip(rint(sigmoid(x_f)/sy[r])); y_f = y_q*sy[r]
//   out = clip(rint(x_f*y_f/so[r]))
// Output float32 buffer: [S*H] values, then [S] scale_out copy.
//
// R2: per-row 255-entry LUT (x is int8-valued), bit-identical math to the
// R1-passing kernel, evaluated once per value instead of per element.
// R4 (this): 4 rows per block with ALL barriers except one removed.
//   - 2048 blocks x 4 consecutive rows (scalar-load latency + LUT build
//     amortized 4x).
//   - All 4 per-row LUTs are built up front into lut[4][256] (4 KB LDS; each
//     thread evaluates 4 points — same total work as 1 point x 4 rows).
//     After the single __syncthreads() the LUTs are READ-ONLY, so the 4-row
//     load->gather->store loop needs no further barriers: row r+1's
//     nontemporal loads are issued before row r's gather/store and stay in
//     flight across rows with counted vmcnt waits (compiler-inserted).
//   - No raw s_barrier / inline-asm waitcnt anywhere (R3's only risky
//     construct, dropped in case it was what killed the container).
//
// Numerics: y-path untouched (expf + two IEEE divs) — a y-flip in a row with
// s_y~s_o can cost ~|xf| (~6) quant steps. Final requant uses per-row
// reciprocal (flips there cost at most +-1, absmax stays 1.0).
// Nontemporal: x and out are each touched exactly once -> bypass cache alloc.

#define SEQ_LEN 8192
#define HIDDEN  4096
#define QMAX_F  127.0f
#define THREADS 256
#define VPT     4                    // iv4 vectors per thread per row: 256*4*4 = 4096
#define ROWS_PB 4                    // rows per block
#define NBLOCKS (SEQ_LEN / ROWS_PB)  // 2048
#define ROW_V   (HIDDEN / 4)         // 1024 iv4 per row

typedef int   iv4 __attribute__((ext_vector_type(4)));
typedef float fv4 __attribute__((ext_vector_type(4)));

__device__ __forceinline__ float silu_q_one(int xi, float s_x, float s_y,
                                            float r_o) {
    float xf  = (float)xi * s_x;                 // dequant (exact)
    float e   = expf(-xf);                       // ~1 ulp vs np.exp
    float sig = 1.0f / (1.0f + e);               // IEEE div (unchanged)
    float yq  = rintf(sig / s_y);                // IEEE div (unchanged)
    yq        = fminf(fmaxf(yq, -QMAX_F), QMAX_F);
    float yf  = yq * s_y;
    float of  = xf * yf;
    float oq  = rintf(of * r_o);                 // reciprocal-mul: flip cost <= 1
    return fminf(fmaxf(oq, -QMAX_F), QMAX_F);
}

__global__ __launch_bounds__(THREADS) void silu_quant_kernel(
    const int*   __restrict__ x,
    const float* __restrict__ scale_x,
    const float* __restrict__ scale_y,
    const float* __restrict__ scale_out,
    float*       __restrict__ out)
{
    __shared__ float lut[ROWS_PB][256];          // 4 KB: one LUT per row

    const int r0 = blockIdx.x * ROWS_PB;
    const int t  = threadIdx.x;

    // Per-row scales (block-uniform -> scalar regs; latency paid once).
    float sx[ROWS_PB], sy[ROWS_PB], so[ROWS_PB], ro[ROWS_PB];
    #pragma unroll
    for (int r = 0; r < ROWS_PB; ++r) {
        sx[r] = scale_x[r0 + r];
        sy[r] = scale_y[r0 + r];
        so[r] = scale_out[r0 + r];
        ro[r] = 1.0f / so[r];
    }

    const iv4* __restrict__ xrow0 = (const iv4*)(x + (size_t)r0 * HIDDEN);
    fv4*       __restrict__ orow0 = (fv4*)(out + (size_t)r0 * HIDDEN);

    // Double-buffered register tile; fully unrolled -> compile-time indices.
    iv4 xb[2][VPT];

    // Row 0 loads issue first: their HBM latency overlaps the LUT build.
    #pragma unroll
    for (int k = 0; k < VPT; ++k)
        xb[0][k] = __builtin_nontemporal_load(xrow0 + t + k * THREADS);

    // Build ALL per-row LUTs (identical ops to the R1 per-element path).
    if (t < 255) {
        #pragma unroll
        for (int r = 0; r < ROWS_PB; ++r)
            lut[r][t] = silu_q_one(t - 127, sx[r], sy[r], ro[r]);
    }

    // Tuple output #2: scale_out appended after the matrix.
    if (t == 255) {
        #pragma unroll
        for (int r = 0; r < ROWS_PB; ++r)
            out[(size_t)SEQ_LEN * HIDDEN + r0 + r] = so[r];
    }

    __syncthreads();   // the ONLY barrier: LUTs are read-only afterwards

    // Barrier-free pipelined row loop: prefetch r+1, then gather/store r.
    #pragma unroll
    for (int r = 0; r < ROWS_PB; ++r) {
        const int cur = r & 1;

        if (r + 1 < ROWS_PB) {
            #pragma unroll
            for (int k = 0; k < VPT; ++k)
                xb[cur ^ 1][k] = __builtin_nontemporal_load(
                    xrow0 + (size_t)(r + 1) * ROW_V + t + k * THREADS);
        }

        const float* lutc = &lut[r][127];        // index directly by xi
        #pragma unroll
        for (int k = 0; k < VPT; ++k) {
            iv4 xv = xb[cur][k];
            fv4 o;
            o.x = lutc[xv.x];
            o.y = lutc[xv.y];
            o.z = lutc[xv.z];
            o.w = lutc[xv.w];
            __builtin_nontemporal_store(
                o, orow0 + (size_t)r * ROW_V + t + k * THREADS);
        }
    }
}

extern "C" void kernel_launch(void* const* d_in, const int* in_sizes, int n_in,
                              void* d_out, int out_size, void* d_ws, size_t ws_size,
                              hipStream_t stream) {
    const int*   x         = (const int*)  d_in[0];
    const float* scale_x   = (const float*)d_in[1];
    const float* scale_y   = (const float*)d_in[2];
    const float* scale_out = (const float*)d_in[3];
    float*       out       = (float*)d_out;

    silu_quant_kernel<<<NBLOCKS, THREADS, 0, stream>>>(
        x, scale_x, scale_y, scale_out, out);
}